// Round 10
// baseline (233.694 us; speedup 1.0000x reference)
//
#include <hip/hip_runtime.h>
#include <cmath>

#define T_SEQ 1024
#define EMB   1024
#define NH    16
#define HD    64
#define NB    4
#define BQ    128
#define BK    64

// softmax computed in log2 domain: exp(x) == exp2(x * log2e)
#define QSCALE 0.18033688011112042f   /* 0.125 * log2(e) */
#define BIAS2  -1.44269504e9f         /* -1e9 * log2(e) */

using frag8   = __attribute__((ext_vector_type(8))) short;
using f32x4   = __attribute__((ext_vector_type(4))) float;
using short4v = __attribute__((ext_vector_type(4))) short;
using short8v = __attribute__((ext_vector_type(8))) short;

__device__ inline short f2bf(float f) {               // RNE
    union { float f; unsigned u; } x; x.f = f;
    unsigned r = (x.u + 0x7FFFu + ((x.u >> 16) & 1u)) >> 16;
    return (short)r;
}
__device__ inline float bf2f(unsigned short u) {
    union { unsigned u; float f; } x; x.u = ((unsigned)u) << 16;
    return x.f;
}
// pack 2 f32 -> dword of 2 bf16 (lo = src0, hi = src1); T12 recipe
__device__ inline int cvt_pk_bf16(float lo, float hi) {
    int r;
    asm("v_cvt_pk_bf16_f32 %0, %1, %2" : "=v"(r) : "v"(lo), "v"(hi));
    return r;
}
// pack 4 f32 -> short4v via two cvt_pk (union: vector-elem addr is illegal)
__device__ inline short4v pack4(float v0, float v1, float v2, float v3) {
    union { int i[2]; short4v s; } u;
    u.i[0] = cvt_pk_bf16(v0, v1);
    u.i[1] = cvt_pk_bf16(v2, v3);
    return u.s;
}

__device__ inline void glds16(const short* g, short* l) {
    __builtin_amdgcn_global_load_lds(
        (const __attribute__((address_space(1))) void*)g,
        (__attribute__((address_space(3))) void*)l, 16, 0, 0);
}

// ---------------------------------------------------------------------------
// Fused preprocessing, ONE launch:
//   blocks 0..6143    : fp32->bf16 inputs (q,k,v), 2048 blocks each
//   blocks 6144..8191 : fp32->bf16 weights (Wq,Wk,Wv,Wo), 512 each
//   blocks 8192..12287: mask int32 -> bf16 additive bias, transposed
//                       fragment-tile layout
// ---------------------------------------------------------------------------
struct ConvArgs {
    const float* src[7]; short* dst[7];
    const int* mask; short* maskb;
};

__global__ __launch_bounds__(256) void convert_all(ConvArgs a) {
    const int bid = blockIdx.x;
    if (bid < 8192) {
        int y, t;
        if (bid < 6144) { y = bid >> 11; t = ((bid & 2047) << 8) | threadIdx.x; }
        else { const int r = bid - 6144; y = 3 + (r >> 9); t = ((r & 511) << 8) | threadIdx.x; }
        const float4* s = (const float4*)a.src[y];
        const float4 v0 = s[t * 2], v1 = s[t * 2 + 1];
        short8v o;
        o[0] = f2bf(v0.x); o[1] = f2bf(v0.y); o[2] = f2bf(v0.z); o[3] = f2bf(v0.w);
        o[4] = f2bf(v1.x); o[5] = f2bf(v1.y); o[6] = f2bf(v1.z); o[7] = f2bf(v1.w);
        *(short8v*)&a.dst[y][t * 8] = o;
    } else {
        const int wave = threadIdx.x >> 6, lane = threadIdx.x & 63;
        const int tile = (bid - 8192) * 4 + wave;    // (b*64+q16)*64+k16
        const int bb   = tile >> 12;
        const int q16  = (tile >> 6) & 63;
        const int k16  = tile & 63;
        const int qrow = lane >> 2;                  // q row within tile
        const int col4 = (lane & 3) * 4;             // key cols
        const int4 mv = *(const int4*)&a.mask[((size_t)bb * T_SEQ + q16 * 16 + qrow) * T_SEQ
                                              + k16 * 16 + col4];
        const short BB = f2bf(BIAS2);
        short4v o;
        o[0] = mv.x ? (short)0 : BB;
        o[1] = mv.y ? (short)0 : BB;
        o[2] = mv.z ? (short)0 : BB;
        o[3] = mv.w ? (short)0 : BB;
        *(short4v*)&a.maskb[(size_t)tile * 256 + qrow * 16 + col4] = o;
    }
}

// ---------------------------------------------------------------------------
// bf16 MFMA GEMM core: C = (A(MxK_span) @ W^T + bias?) * scale
// 0-phase BK=64 schedule (R8-proven; panel-pipelining regressed, R7).
// v10 (= v9 + compile fix): VECTORIZED EPILOGUES. MFMA C-layout puts reg(rr)
// on the FIRST operand's row dim. For MODE 0/1 we SWAP operand order
// (mfma(bF,aF)) so rr maps to the n-dim (d) -> consecutive d at fixed t are
// contiguous in the frag layouts -> one short4/float4 store + 2 cvt_pk per
// (i,j) instead of 4 scalar stores + 12 VALU. MODE 2's layout is already
// rr-contiguous UNSWAPPED (inner = (tt&16)>>2 + rr) — packed too.
// 64 scalar stores -> 16 vector stores per thread in all modes.
// MODE 0: fp32, layout ((m>>4)*64+(n>>4))*256 + (m&15)*16 + (n&15)
//         (swapped: GEMM store wave-contiguous AND LN read float4)
// MODE 1: bf16 A-frag order [bh][t16][d8][t%16][d&7]  (flash Q/K reads)
// MODE 2: bf16 V^T frag, pi-permuted key order (flash PV reads)
// ---------------------------------------------------------------------------
struct GemmB { const short* A; const short* W; const float* bias; short* out; float scale; };
struct QkvArgs { GemmB g[3]; };

template <int MODE>
__device__ inline void gemm_core(short* __restrict__ As,
                                 short* __restrict__ Bs,
                                 const short* __restrict__ A,
                                 const short* __restrict__ W,
                                 const float* __restrict__ bias,
                                 float scale,
                                 short* __restrict__ outS,
                                 float* __restrict__ outF,
                                 int m0, int n0, int k0, int kspan)
{
    const int tid  = threadIdx.x;
    const int wave = tid >> 6;
    const int lane = tid & 63;
    const int quad = lane >> 4;
    const int lm   = lane & 15;
    const int wr   = wave >> 1;
    const int wc   = wave & 1;
    const int K    = EMB;

    const int G0 = wave * 64 + lane, G1 = G0 + 256;
    const short* aSrc0 = A + (size_t)(m0 + (G0 >> 2)) * K + (G0 & 3) * 8;
    const short* aSrc1 = A + (size_t)(m0 + (G1 >> 2)) * K + (G1 & 3) * 8;
    const short* bSrc0 = W + (size_t)(n0 + (G0 >> 2)) * K + (G0 & 3) * 8;
    const short* bSrc1 = W + (size_t)(n0 + (G1 >> 2)) * K + (G1 & 3) * 8;
    short* aDst0 = As + wave * 512;
    short* aDst1 = As + 2048 + wave * 512;
    short* bDst0 = Bs + wave * 512;
    short* bDst1 = Bs + 2048 + wave * 512;

    f32x4 acc[4][4];
#pragma unroll
    for (int i = 0; i < 4; ++i)
#pragma unroll
        for (int j = 0; j < 4; ++j) acc[i][j] = (f32x4){0.f, 0.f, 0.f, 0.f};

    for (int kk = k0; kk < k0 + kspan; kk += 64) {
        __syncthreads();
        glds16(aSrc0 + kk,      aDst0);
        glds16(aSrc1 + kk,      aDst1);
        glds16(bSrc0 + kk,      bDst0);
        glds16(bSrc1 + kk,      bDst1);
        glds16(aSrc0 + kk + 32, aDst0 + 4096);
        glds16(aSrc1 + kk + 32, aDst1 + 4096);
        glds16(bSrc0 + kk + 32, bDst0 + 4096);
        glds16(bSrc1 + kk + 32, bDst1 + 4096);
        __syncthreads();

#pragma unroll
        for (int p = 0; p < 2; ++p) {
            frag8 aF[4], bF[4];
#pragma unroll
            for (int i = 0; i < 4; ++i)
                aF[i] = *(const frag8*)&As[p * 4096 + (wr * 64 + i * 16 + lm) * 32 + quad * 8];
#pragma unroll
            for (int j = 0; j < 4; ++j)
                bF[j] = *(const frag8*)&Bs[p * 4096 + (wc * 64 + j * 16 + lm) * 32 + quad * 8];
#pragma unroll
            for (int i = 0; i < 4; ++i)
#pragma unroll
                for (int j = 0; j < 4; ++j) {
                    if (MODE == 2)   // rows(reg)=m, cols(lm)=n
                        acc[i][j] = __builtin_amdgcn_mfma_f32_16x16x32_bf16(
                            aF[i], bF[j], acc[i][j], 0, 0, 0);
                    else             // SWAPPED: rows(reg)=n, cols(lm)=m
                        acc[i][j] = __builtin_amdgcn_mfma_f32_16x16x32_bf16(
                            bF[i], aF[j], acc[i][j], 0, 0, 0);
                }
        }
    }

    if (MODE == 2) {
        // i = m-frags (rows: m = m0+wr*64+i*16+quad*4+rr), j = n-frags
        // (cols: n = n0+wc*64+j*16+lm). rr -> tt consecutive; pi inner
        // index = ((tt&16)>>2) + rr -> short4-contiguous.
#pragma unroll
        for (int i = 0; i < 4; ++i)
#pragma unroll
            for (int j = 0; j < 4; ++j) {
                const int n = n0 + wc * 64 + j * 16 + lm;
                const float bv = bias[n];
                const int m_abs = m0 + wr * 64 + i * 16 + quad * 4;
                const int bb = m_abs >> 10, tt = m_abs & 1023;
                const int h = n >> 6, d = n & 63;
                const size_t bh = (size_t)bb * NH + h;
                const size_t addr =
                    ((((bh * 16 + (tt >> 6)) * 2 + ((tt >> 5) & 1)) * 4 +
                      (d >> 4)) * 4 + ((tt >> 2) & 3)) * 128 +
                    (d & 15) * 8 + ((tt & 16) >> 2);
                *(short4v*)&outS[addr] =
                    pack4((acc[i][j][0] + bv) * scale, (acc[i][j][1] + bv) * scale,
                          (acc[i][j][2] + bv) * scale, (acc[i][j][3] + bv) * scale);
            }
    } else {
        // SWAPPED: i = n-frags (rows: n = n0+wc*64+i*16+quad*4+rr),
        //          j = m-frags (cols: m = m0+wr*64+j*16+lm).
#pragma unroll
        for (int i = 0; i < 4; ++i) {
            const int n_base = n0 + wc * 64 + i * 16 + quad * 4;
            float4 bv4 = make_float4(0.f, 0.f, 0.f, 0.f);
            if (k0 == 0) bv4 = *(const float4*)&bias[n_base];
#pragma unroll
            for (int j = 0; j < 4; ++j) {
                const int m = m0 + wr * 64 + j * 16 + lm;
                const float v0 = (acc[i][j][0] + bv4.x) * scale;
                const float v1 = (acc[i][j][1] + bv4.y) * scale;
                const float v2 = (acc[i][j][2] + bv4.z) * scale;
                const float v3 = (acc[i][j][3] + bv4.w) * scale;
                if (MODE == 0) {
                    const size_t addr = ((size_t)(m >> 4) * 64 + (n_base >> 4)) * 256 +
                                        lm * 16 + (n_base & 15);
                    *(float4*)&outF[addr] = make_float4(v0, v1, v2, v3);
                } else {
                    const int bb = m >> 10, tt = m & 1023;
                    const int h = n_base >> 6, d = n_base & 63;
                    const size_t bh = (size_t)bb * NH + h;
                    const size_t addr = ((bh * 64 + (tt >> 4)) * 8 + (d >> 3)) * 128 +
                                        lm * 8 + (d & 7);
                    *(short4v*)&outS[addr] = pack4(v0, v1, v2, v3);
                }
            }
        }
    }
}

// XCD-colocating swizzle: all 8 n-blocks of one (m,z) share an XCD slot.
__global__ __launch_bounds__(256, 4) void gemm_qkv(QkvArgs args) {
    __shared__ short As[2 * 128 * 32];
    __shared__ short Bs[2 * 128 * 32];
    const int id = blockIdx.x + 8 * blockIdx.y + 256 * blockIdx.z;  // 0..767
    const int a  = id & 7;
    const int k2 = id >> 3;          // 0..95
    const int nb = k2 & 7;
    const int c  = k2 >> 3;          // 0..11
    const int pair = a * 12 + c;     // 0..95
    const int mb = pair & 31;
    const int zb = pair >> 5;        // 0..2
    const GemmB g = args.g[zb];
    if (zb < 2) gemm_core<1>(As, Bs, g.A, g.W, g.bias, g.scale, g.out, nullptr,
                             mb * 128, nb * 128, 0, EMB);
    else        gemm_core<2>(As, Bs, g.A, g.W, g.bias, g.scale, g.out, nullptr,
                             mb * 128, nb * 128, 0, EMB);
}

// Split-K x2: 512 blocks -> 2 blocks/CU (1 block/CU was the occupancy floor).
__global__ __launch_bounds__(256, 4) void gemm_wo(const short* __restrict__ A,
                                                  const short* __restrict__ W,
                                                  const float* __restrict__ bias,
                                                  float* __restrict__ out0,
                                                  float* __restrict__ out1) {
    __shared__ short As[2 * 128 * 32];
    __shared__ short Bs[2 * 128 * 32];
    const int id = blockIdx.x + 8 * blockIdx.y;   // 0..511
    const int a  = id & 7;
    const int r  = id >> 3;          // 0..63
    const int nb = r & 7;
    const int pr = a * 8 + (r >> 3); // 0..63
    const int mb = pr & 31;
    const int ks = pr >> 5;          // 0..1
    gemm_core<0>(As, Bs, A, W, bias, 1.0f, nullptr, ks ? out1 : out0,
                 mb * 128, nb * 128, ks * 512, 512);
}

// ---------------------------------------------------------------------------
// Flash attention, S^T form: S^T = MFMA(A=K, B=Q); q on lm, keys on quad/regs.
//  BQ=128, no split-K; 8 wq waves x 16 q-rows; 16 serial key tiles with the
//  2-phase pipeline (stage kt+1 early, one barrier/iter); LDS 32KB.
//  - P^T in registers via cvt_pk (pi-permuted V^T from gemm MODE 2).
//  - lsum via all-ones-A MFMA; ls[0] is directly the softmax denominator.
// ---------------------------------------------------------------------------
__global__ __launch_bounds__(512, 4) void flash_attn_mfma(
    const short* __restrict__ qf_, const short* __restrict__ kf_,
    const short* __restrict__ vf_, const short* __restrict__ mf_,
    short* __restrict__ out)
{
    __shared__ short KV[2][2][4096];  // 32KB: [parity][K,V][8KB tile]

    const int tid  = threadIdx.x;
    const int wave = tid >> 6;           // wq: q sub-tile (16 rows)
    const int lane = tid & 63;
    const int quad = lane >> 4;
    const int lm   = lane & 15;

    const int id  = blockIdx.x;          // 0..511
    const int xcd = id & 7;
    const int idx = id >> 3;             // 0..63
    const int bh_i = xcd * 8 + (idx >> 3);   // 0..63
    const int b  = bh_i >> 4, h = bh_i & 15;
    const int qb = idx & 7;              // q block (128 rows)
    const int q0 = qb * BQ;
    const size_t bh = (size_t)bh_i;

    // staging: waves 0-3 stage the K tile (2KB chunks), waves 4-7 the V tile.
    const short* sbase = ((wave < 4) ? kf_ : vf_) + bh * 65536
                         + (wave & 3) * 1024 + lane * 8;
    short* dstb = &KV[0][0][0] + (wave >> 2) * 4096 + (wave & 3) * 1024;

    // Q fragments (lane-ordered coalesced loads) — used as B operand
    const short* qb_ = qf_ + (bh * 64 + qb * 8 + wave) * 1024;
    const frag8 qfa = *(const frag8*)&qb_[(quad * 16 + lm) * 8];
    const frag8 qfb = *(const frag8*)&qb_[((quad + 4) * 16 + lm) * 8];

    // transposed mask tiles: [q%16][key%16]; this lane: q=lm, keys=quad*4..+3
    const short* mrow = mf_ + ((size_t)b * 64 + qb * 8 + wave) * (64 * 256)
                        + lm * 16 + quad * 4;

    // all-ones A fragment for the lsum MFMA
    union { int i[4]; frag8 f; } ones;
    ones.i[0] = ones.i[1] = ones.i[2] = ones.i[3] = 0x3F803F80;

    f32x4 of[4];
#pragma unroll
    for (int dc = 0; dc < 4; ++dc) of[dc] = (f32x4){0.f, 0.f, 0.f, 0.f};
    f32x4 ls = (f32x4){0.f, 0.f, 0.f, 0.f};

    // ---- prologue: stage kt=0 into parity 0; prefetch mask(kt=0) ----
    glds16(sbase,       dstb);
    glds16(sbase + 512, dstb + 512);
    short4v mb[4];
#pragma unroll
    for (int kc = 0; kc < 4; ++kc)
        mb[kc] = *(const short4v*)&mrow[kc * 256];
    __syncthreads();                     // drains prologue stage

    for (int kt = 0; kt < 16; ++kt) {
        const int cur = kt & 1;

        // issue next tile's stage EARLY — latency hides under compute below
        if (kt < 15) {
            short* nd = dstb + (cur ^ 1) * 8192;
            glds16(sbase + (kt + 1) * 4096,       nd);
            glds16(sbase + (kt + 1) * 4096 + 512, nd + 512);
        }
        // current mask to working regs; prefetch next tile's mask
        short4v mc[4];
#pragma unroll
        for (int kc = 0; kc < 4; ++kc) mc[kc] = mb[kc];
        if (kt < 15) {
#pragma unroll
            for (int kc = 0; kc < 4; ++kc)
                mb[kc] = *(const short4v*)&mrow[((kt + 1) * 4 + kc) * 256];
        }

        // S^T = K Q^T + maskbias (acc-init): rows=keys, cols=q
        f32x4 s[4];
#pragma unroll
        for (int kc = 0; kc < 4; ++kc) {
            const short* kb = &KV[cur][0][kc * 1024];
            const frag8 kfa = *(const frag8*)&kb[(quad * 16 + lm) * 8];
            const frag8 kfb = *(const frag8*)&kb[((quad + 4) * 16 + lm) * 8];
            f32x4 a = (f32x4){ bf2f((unsigned short)mc[kc][0]),
                               bf2f((unsigned short)mc[kc][1]),
                               bf2f((unsigned short)mc[kc][2]),
                               bf2f((unsigned short)mc[kc][3]) };
            a = __builtin_amdgcn_mfma_f32_16x16x32_bf16(kfa, qfa, a, 0, 0, 0);
            a = __builtin_amdgcn_mfma_f32_16x16x32_bf16(kfb, qfb, a, 0, 0, 0);
            s[kc] = a;
        }

        // fixed-max softmax in place: s = exp2(s^T)
#pragma unroll
        for (int kc = 0; kc < 4; ++kc) {
            s[kc][0] = exp2f(s[kc][0]); s[kc][1] = exp2f(s[kc][1]);
            s[kc][2] = exp2f(s[kc][2]); s[kc][3] = exp2f(s[kc][3]);
        }

        // in-register P^T fragments: lane (quad g) holds keys kc*16+4g..+3 —
        // exactly the pi slots (G=g) of the B operand.
        union { int i[4]; frag8 f; } ua, ub;
        ua.i[0] = cvt_pk_bf16(s[0][0], s[0][1]);
        ua.i[1] = cvt_pk_bf16(s[0][2], s[0][3]);
        ua.i[2] = cvt_pk_bf16(s[1][0], s[1][1]);
        ua.i[3] = cvt_pk_bf16(s[1][2], s[1][3]);
        ub.i[0] = cvt_pk_bf16(s[2][0], s[2][1]);
        ub.i[1] = cvt_pk_bf16(s[2][2], s[2][3]);
        ub.i[2] = cvt_pk_bf16(s[3][0], s[3][1]);
        ub.i[3] = cvt_pk_bf16(s[3][2], s[3][3]);

        __builtin_amdgcn_s_setprio(1);
#pragma unroll
        for (int dc = 0; dc < 4; ++dc) {
            const frag8 v0 = *(const frag8*)&KV[cur][1][(dc * 4 + quad) * 128 + lm * 8];
            const frag8 v1 = *(const frag8*)&KV[cur][1][((4 + dc) * 4 + quad) * 128 + lm * 8];
            of[dc] = __builtin_amdgcn_mfma_f32_16x16x32_bf16(v0, ua.f, of[dc], 0, 0, 0);
            of[dc] = __builtin_amdgcn_mfma_f32_16x16x32_bf16(v1, ub.f, of[dc], 0, 0, 0);
        }
        // lsum: D[r][q] = sum_k P[k][q] for every r (A = ones)
        ls = __builtin_amdgcn_mfma_f32_16x16x32_bf16(ones.f, ua.f, ls, 0, 0, 0);
        ls = __builtin_amdgcn_mfma_f32_16x16x32_bf16(ones.f, ub.f, ls, 0, 0, 0);
        __builtin_amdgcn_s_setprio(0);

        // single end-of-iter barrier: next stage drained (vmcnt0) AND all
        // waves done reading KV[cur] (overwritten at kt+2).
        __syncthreads();
    }

    // full denominator is lane-local (no key split)
    const float inv = 1.0f / ls[0];

    // O^T C-layout: row = d = dc*16 + quad*4 + rr, col = q = lm.
    short* ob = out + ((size_t)b * T_SEQ + q0 + wave * 16 + lm) * EMB + h * HD;
#pragma unroll
    for (int dc = 0; dc < 4; ++dc) {
        *(short4v*)&ob[dc * 16 + quad * 4] =
            pack4(of[dc][0] * inv, of[dc][1] * inv,
                  of[dc][2] * inv, of[dc][3] * inv);
    }
}

// ---------------------------------------------------------------------------
// LayerNorm over last dim (1024); sums the two split-K partials of the Wo
// projection (swapped MODE 0 layout: ((m>>4)*64+(n>>4))*256+(m&15)*16+(n&15)
// -> float4 reads), writes row-major.
// ---------------------------------------------------------------------------
__global__ __launch_bounds__(256) void layernorm_k(
    const float* __restrict__ x0, const float* __restrict__ x1,
    const float* __restrict__ gamma, const float* __restrict__ beta,
    float* __restrict__ out)
{
    __shared__ float ws1[4], ws2[4];
    const int tid = threadIdx.x;
    const int row = blockIdx.x;

    const size_t ix = ((size_t)(row >> 4) * 64 + (tid >> 2)) * 256 +
                      (row & 15) * 16 + (tid & 3) * 4;
    const float4 v1 = *(const float4*)&x0[ix];
    const float4 v2 = *(const float4*)&x1[ix];
    float4 v;
    v.x = v1.x + v2.x; v.y = v1.y + v2.y;
    v.z = v1.z + v2.z; v.w = v1.w + v2.w;

    float s  = v.x + v.y + v.z + v.w;
    float ss = v.x * v.x + v.y * v.y + v.z * v.z + v.w * v.w;
#pragma unroll
    for (int off = 32; off > 0; off >>= 1) {
        s  += __shfl_down(s, off);
        ss += __shfl_down(ss, off);
    }
    if ((tid & 63) == 0) { ws1[tid >> 6] = s; ws2[tid >> 6] = ss; }
    __syncthreads();
    if (tid == 0) {
        const float a = ws1[0] + ws1[1] + ws1[2] + ws1[3];
        const float bsum = ws2[0] + ws2[1] + ws2[2] + ws2[3];
        const float mu = a * (1.0f / EMB);
        const float var = bsum * (1.0f / EMB) - mu * mu;
        ws1[0] = mu;
        ws2[0] = rsqrtf(var + 1e-5f);
    }
    __syncthreads();
    const float mu = ws1[0], rstd = ws2[0];

    const float4 g = *(const float4*)&gamma[tid * 4];
    const float4 bt = *(const float4*)&beta[tid * 4];
    float4 r;
    r.x = (v.x - mu) * rstd * g.x + bt.x;
    r.y = (v.y - mu) * rstd * g.y + bt.y;
    r.z = (v.z - mu) * rstd * g.z + bt.z;
    r.w = (v.w - mu) * rstd * g.w + bt.w;
    *(float4*)&out[(size_t)row * EMB + tid * 4] = r;
}

// ---------------------------------------------------------------------------
extern "C" void kernel_launch(void* const* d_in, const int* in_sizes, int n_in,
                              void* d_out, int out_size, void* d_ws, size_t ws_size,
                              hipStream_t stream) {
    const float* query = (const float*)d_in[0];
    const float* key_i = (const float*)d_in[1];
    const float* value = (const float*)d_in[2];
    const int*   mask  = (const int*)d_in[3];
    const float* Wq = (const float*)d_in[4];
    const float* bq = (const float*)d_in[5];
    const float* Wk = (const float*)d_in[6];
    const float* bk = (const float*)d_in[7];
    const float* Wv = (const float*)d_in[8];
    const float* bv = (const float*)d_in[9];
    const float* Wo = (const float*)d_in[10];
    const float* bo = (const float*)d_in[11];
    const float* gamma = (const float*)d_in[12];
    const float* beta  = (const float*)d_in[13];

    const size_t SZ = (size_t)NB * T_SEQ * EMB;   // 4.19M elements
    const size_t WZ = (size_t)EMB * EMB;          // 1.05M elements
    short* sws = (short*)d_ws;
    short* q_bf  = sws;               // dead after gemm_qkv; attnb overlays
    short* k_bf  = sws + SZ;          // dead after gemm_qkv; projb overlays
    short* v_bf  = sws + 2 * SZ;
    short* w_bf  = sws + 3 * SZ;      // Wq,Wk,Wv,Wo bf16 (4*WZ == SZ)
    short* qh    = sws + 4 * SZ;      // Q A-frag layout; dead after flash
    short* kh    = sws + 5 * SZ;      // K A-frag layout; dead after flash
    short* vh    = sws + 6 * SZ;      // V^T frag layout (pi-permuted)
    short* maskb = sws + 7 * SZ;      // bf16 bias, transposed frag tiles
    short* attnb = q_bf;
    float* projb  = (float*)(sws + SZ);      // k_bf/v_bf region (dead)
    float* projb2 = (float*)(sws + 4 * SZ);  // qh/kh region (dead after flash)

    // 1. fused preprocessing (inputs + weights + mask), one launch
    ConvArgs ca;
    ca.src[0] = query; ca.dst[0] = q_bf;
    ca.src[1] = key_i; ca.dst[1] = k_bf;
    ca.src[2] = value; ca.dst[2] = v_bf;
    ca.src[3] = Wq;    ca.dst[3] = w_bf;
    ca.src[4] = Wk;    ca.dst[4] = w_bf + WZ;
    ca.src[5] = Wv;    ca.dst[5] = w_bf + 2 * WZ;
    ca.src[6] = Wo;    ca.dst[6] = w_bf + 3 * WZ;
    ca.mask = mask; ca.maskb = maskb;
    convert_all<<<dim3(12288), 256, 0, stream>>>(ca);

    // 2. QKV projections; Q pre-scaled by 0.125*log2e; frag-layout outputs
    QkvArgs qa;
    qa.g[0] = { q_bf, w_bf,          bq, qh, QSCALE };
    qa.g[1] = { k_bf, w_bf + WZ,     bk, kh, 1.0f };
    qa.g[2] = { v_bf, w_bf + 2 * WZ, bv, vh, 1.0f };
    gemm_qkv<<<dim3(EMB / 128, NB * T_SEQ / 128, 3), 256, 0, stream>>>(qa);

    // 3. flash attention (BQ=128, 2-phase pipeline, XCD grid)
    flash_attn_mfma<<<dim3(T_SEQ / BQ * NH * NB), 512, 0, stream>>>(qh, kh, vh, maskb, attnb);

    // 4. output projection, split-K x2 (fp32 swapped C-order partials)
    gemm_wo<<<dim3(8, 64), 256, 0, stream>>>(attnb, w_bf + 3 * WZ, bo, projb, projb2);

    // 5. layernorm (sums partials, writes row-major)
    layernorm_k<<<dim3(NB * T_SEQ), 256, 0, stream>>>(projb, projb2, gamma, beta, (float*)d_out);
}

// Round 11
// 227.939 us; speedup vs baseline: 1.0252x; 1.0252x over previous
//
#include <hip/hip_runtime.h>
#include <cmath>

#define T_SEQ 1024
#define EMB   1024
#define NH    16
#define HD    64
#define NB    4
#define BQ    128
#define BK    64

// softmax computed in log2 domain: exp(x) == exp2(x * log2e)
#define QSCALE 0.18033688011112042f   /* 0.125 * log2(e) */
#define BIAS2  -1.44269504e9f         /* -1e9 * log2(e) */

using frag8   = __attribute__((ext_vector_type(8))) short;
using f32x4   = __attribute__((ext_vector_type(4))) float;
using short4v = __attribute__((ext_vector_type(4))) short;
using short8v = __attribute__((ext_vector_type(8))) short;

__device__ inline short f2bf(float f) {               // RNE
    union { float f; unsigned u; } x; x.f = f;
    unsigned r = (x.u + 0x7FFFu + ((x.u >> 16) & 1u)) >> 16;
    return (short)r;
}
__device__ inline float bf2f(unsigned short u) {
    union { unsigned u; float f; } x; x.u = ((unsigned)u) << 16;
    return x.f;
}
// pack 2 f32 -> dword of 2 bf16 (lo = src0, hi = src1); T12 recipe
__device__ inline int cvt_pk_bf16(float lo, float hi) {
    int r;
    asm("v_cvt_pk_bf16_f32 %0, %1, %2" : "=v"(r) : "v"(lo), "v"(hi));
    return r;
}
// pack 4 f32 -> short4v via two cvt_pk (union: vector-elem addr is illegal)
__device__ inline short4v pack4(float v0, float v1, float v2, float v3) {
    union { int i[2]; short4v s; } u;
    u.i[0] = cvt_pk_bf16(v0, v1);
    u.i[1] = cvt_pk_bf16(v2, v3);
    return u.s;
}

__device__ inline void glds16(const short* g, short* l) {
    __builtin_amdgcn_global_load_lds(
        (const __attribute__((address_space(1))) void*)g,
        (__attribute__((address_space(3))) void*)l, 16, 0, 0);
}

// ---------------------------------------------------------------------------
// Fused preprocessing, ONE launch:
//   blocks 0..6143    : fp32->bf16 inputs (q,k,v), 2048 blocks each
//   blocks 6144..8191 : fp32->bf16 weights (Wq,Wk,Wv,Wo), 512 each
//   blocks 8192..12287: mask int32 -> bf16 additive bias, transposed
//                       fragment-tile layout
// ---------------------------------------------------------------------------
struct ConvArgs {
    const float* src[7]; short* dst[7];
    const int* mask; short* maskb;
};

__global__ __launch_bounds__(256) void convert_all(ConvArgs a) {
    const int bid = blockIdx.x;
    if (bid < 8192) {
        int y, t;
        if (bid < 6144) { y = bid >> 11; t = ((bid & 2047) << 8) | threadIdx.x; }
        else { const int r = bid - 6144; y = 3 + (r >> 9); t = ((r & 511) << 8) | threadIdx.x; }
        const float4* s = (const float4*)a.src[y];
        const float4 v0 = s[t * 2], v1 = s[t * 2 + 1];
        short8v o;
        o[0] = f2bf(v0.x); o[1] = f2bf(v0.y); o[2] = f2bf(v0.z); o[3] = f2bf(v0.w);
        o[4] = f2bf(v1.x); o[5] = f2bf(v1.y); o[6] = f2bf(v1.z); o[7] = f2bf(v1.w);
        *(short8v*)&a.dst[y][t * 8] = o;
    } else {
        const int wave = threadIdx.x >> 6, lane = threadIdx.x & 63;
        const int tile = (bid - 8192) * 4 + wave;    // (b*64+q16)*64+k16
        const int bb   = tile >> 12;
        const int q16  = (tile >> 6) & 63;
        const int k16  = tile & 63;
        const int qrow = lane >> 2;                  // q row within tile
        const int col4 = (lane & 3) * 4;             // key cols
        const int4 mv = *(const int4*)&a.mask[((size_t)bb * T_SEQ + q16 * 16 + qrow) * T_SEQ
                                              + k16 * 16 + col4];
        const short BB = f2bf(BIAS2);
        short4v o;
        o[0] = mv.x ? (short)0 : BB;
        o[1] = mv.y ? (short)0 : BB;
        o[2] = mv.z ? (short)0 : BB;
        o[3] = mv.w ? (short)0 : BB;
        *(short4v*)&a.maskb[(size_t)tile * 256 + qrow * 16 + col4] = o;
    }
}

// ---------------------------------------------------------------------------
// bf16 MFMA GEMM core: C = (A(MxK_span) @ W^T + bias?) * scale
// v11: 8-WAVE BLOCKS (512 threads), same 128x128 tile, same 0-phase BK=64
// schedule. R10 counters: MfmaUtil 23 / VALUBusy 12 / HBM 17 / Occ 19.5% —
// all pipes idle at 12 waves/CU; R7 proved intra-wave pipelining can't fix
// this structure, so the lever is TLP: 8 waves x 3 blocks = 24 waves/CU.
// Wave grid 2x4: wr=wave>>2 owns a 64-row m-half, wc=wave&3 a 32-col
// n-quarter; acc halves to 8 f32x4 (32 VGPR) -> launch_bounds(512,6)
// (VGPR cap 85, est. need ~70). Staging: 512 threads cover each 8KB panel
// exactly -> 4 glds16/K-step. L2 traffic identical (same tile geometry).
// Epilogues (R10-vectorized) re-indexed for the new wave grid; output
// layouts bit-identical (flash/LN readers untouched).
// MODE 0: fp32, layout ((m>>4)*64+(n>>4))*256 + (m&15)*16 + (n&15)
// MODE 1: bf16 A-frag order [bh][t16][d8][t%16][d&7]  (flash Q/K reads)
// MODE 2: bf16 V^T frag, pi-permuted key order (flash PV reads)
// MODE 0/1 use SWAPPED operand order (mfma(bF,aF): reg->n) so stores
// vectorize; MODE 2 unswapped (its layout is rr-contiguous in m).
// ---------------------------------------------------------------------------
struct GemmB { const short* A; const short* W; const float* bias; short* out; float scale; };
struct QkvArgs { GemmB g[3]; };

template <int MODE>
__device__ inline void gemm_core(short* __restrict__ As,
                                 short* __restrict__ Bs,
                                 const short* __restrict__ A,
                                 const short* __restrict__ W,
                                 const float* __restrict__ bias,
                                 float scale,
                                 short* __restrict__ outS,
                                 float* __restrict__ outF,
                                 int m0, int n0, int k0, int kspan)
{
    const int tid  = threadIdx.x;
    const int wave = tid >> 6;
    const int lane = tid & 63;
    const int quad = lane >> 4;
    const int lm   = lane & 15;
    const int wr   = wave >> 2;          // m-half   (0..1)
    const int wc   = wave & 3;           // n-quarter (0..3)
    const int K    = EMB;

    // 512 threads cover one 128x32 panel (8KB) exactly: row = tid>>2,
    // col8 = tid&3. LDS offset = tid*8 shorts = wave*512 + lane*8
    // (glds16 wave-uniform-dest rule holds).
    const short* aSrc = A + (size_t)(m0 + (tid >> 2)) * K + (tid & 3) * 8;
    const short* bSrc = W + (size_t)(n0 + (tid >> 2)) * K + (tid & 3) * 8;
    short* aDst = As + wave * 512;
    short* bDst = Bs + wave * 512;

    constexpr int NI = (MODE == 2) ? 4 : 2;
    constexpr int NJ = (MODE == 2) ? 2 : 4;
    f32x4 acc[NI][NJ];
#pragma unroll
    for (int i = 0; i < NI; ++i)
#pragma unroll
        for (int j = 0; j < NJ; ++j) acc[i][j] = (f32x4){0.f, 0.f, 0.f, 0.f};

    for (int kk = k0; kk < k0 + kspan; kk += 64) {
        __syncthreads();
        glds16(aSrc + kk,      aDst);
        glds16(aSrc + kk + 32, aDst + 4096);
        glds16(bSrc + kk,      bDst);
        glds16(bSrc + kk + 32, bDst + 4096);
        __syncthreads();

#pragma unroll
        for (int p = 0; p < 2; ++p) {
            frag8 aF[4], bF[2];
#pragma unroll
            for (int j = 0; j < 4; ++j)
                aF[j] = *(const frag8*)&As[p * 4096 + (wr * 64 + j * 16 + lm) * 32 + quad * 8];
#pragma unroll
            for (int i = 0; i < 2; ++i)
                bF[i] = *(const frag8*)&Bs[p * 4096 + (wc * 32 + i * 16 + lm) * 32 + quad * 8];
            if (MODE == 2) {
                // unswapped: rows(reg)=m, cols(lm)=n; i=m-frag, j=n-frag
#pragma unroll
                for (int i = 0; i < 4; ++i)
#pragma unroll
                    for (int j = 0; j < 2; ++j)
                        acc[i][j] = __builtin_amdgcn_mfma_f32_16x16x32_bf16(
                            aF[i], bF[j], acc[i][j], 0, 0, 0);
            } else {
                // swapped: rows(reg)=n, cols(lm)=m; i=n-frag, j=m-frag
#pragma unroll
                for (int i = 0; i < 2; ++i)
#pragma unroll
                    for (int j = 0; j < 4; ++j)
                        acc[i][j] = __builtin_amdgcn_mfma_f32_16x16x32_bf16(
                            bF[i], aF[j], acc[i][j], 0, 0, 0);
            }
        }
    }

    if (MODE == 2) {
        // m = m0 + wr*64 + i*16 + quad*4 + rr ; n = n0 + wc*32 + j*16 + lm
#pragma unroll
        for (int i = 0; i < 4; ++i)
#pragma unroll
            for (int j = 0; j < 2; ++j) {
                const int n = n0 + wc * 32 + j * 16 + lm;
                const float bv = bias[n];
                const int m_abs = m0 + wr * 64 + i * 16 + quad * 4;
                const int bb = m_abs >> 10, tt = m_abs & 1023;
                const int h = n >> 6, d = n & 63;
                const size_t bh = (size_t)bb * NH + h;
                const size_t addr =
                    ((((bh * 16 + (tt >> 6)) * 2 + ((tt >> 5) & 1)) * 4 +
                      (d >> 4)) * 4 + ((tt >> 2) & 3)) * 128 +
                    (d & 15) * 8 + ((tt & 16) >> 2);
                *(short4v*)&outS[addr] =
                    pack4((acc[i][j][0] + bv) * scale, (acc[i][j][1] + bv) * scale,
                          (acc[i][j][2] + bv) * scale, (acc[i][j][3] + bv) * scale);
            }
    } else {
        // n = n0 + wc*32 + i*16 + quad*4 + rr ; m = m0 + wr*64 + j*16 + lm
#pragma unroll
        for (int i = 0; i < 2; ++i) {
            const int n_base = n0 + wc * 32 + i * 16 + quad * 4;
            float4 bv4 = make_float4(0.f, 0.f, 0.f, 0.f);
            if (k0 == 0) bv4 = *(const float4*)&bias[n_base];
#pragma unroll
            for (int j = 0; j < 4; ++j) {
                const int m = m0 + wr * 64 + j * 16 + lm;
                const float v0 = (acc[i][j][0] + bv4.x) * scale;
                const float v1 = (acc[i][j][1] + bv4.y) * scale;
                const float v2 = (acc[i][j][2] + bv4.z) * scale;
                const float v3 = (acc[i][j][3] + bv4.w) * scale;
                if (MODE == 0) {
                    const size_t addr = ((size_t)(m >> 4) * 64 + (n_base >> 4)) * 256 +
                                        lm * 16 + (n_base & 15);
                    *(float4*)&outF[addr] = make_float4(v0, v1, v2, v3);
                } else {
                    const int bb = m >> 10, tt = m & 1023;
                    const int h = n_base >> 6, d = n_base & 63;
                    const size_t bh = (size_t)bb * NH + h;
                    const size_t addr = ((bh * 64 + (tt >> 4)) * 8 + (d >> 3)) * 128 +
                                        lm * 8 + (d & 7);
                    *(short4v*)&outS[addr] = pack4(v0, v1, v2, v3);
                }
            }
        }
    }
}

// XCD-colocating swizzle: all 8 n-blocks of one (m,z) share an XCD slot.
// 512 threads, 3 blocks/CU -> 24 waves/CU (launch_bounds(512,6): VGPR<=85).
__global__ __launch_bounds__(512, 6) void gemm_qkv(QkvArgs args) {
    __shared__ short As[2 * 128 * 32];
    __shared__ short Bs[2 * 128 * 32];
    const int id = blockIdx.x + 8 * blockIdx.y + 256 * blockIdx.z;  // 0..767
    const int a  = id & 7;
    const int k2 = id >> 3;          // 0..95
    const int nb = k2 & 7;
    const int c  = k2 >> 3;          // 0..11
    const int pair = a * 12 + c;     // 0..95
    const int mb = pair & 31;
    const int zb = pair >> 5;        // 0..2
    const GemmB g = args.g[zb];
    if (zb < 2) gemm_core<1>(As, Bs, g.A, g.W, g.bias, g.scale, g.out, nullptr,
                             mb * 128, nb * 128, 0, EMB);
    else        gemm_core<2>(As, Bs, g.A, g.W, g.bias, g.scale, g.out, nullptr,
                             mb * 128, nb * 128, 0, EMB);
}

// Split-K x2, 512 threads: 2 blocks/CU -> 16 waves/CU.
__global__ __launch_bounds__(512, 4) void gemm_wo(const short* __restrict__ A,
                                                  const short* __restrict__ W,
                                                  const float* __restrict__ bias,
                                                  float* __restrict__ out0,
                                                  float* __restrict__ out1) {
    __shared__ short As[2 * 128 * 32];
    __shared__ short Bs[2 * 128 * 32];
    const int id = blockIdx.x + 8 * blockIdx.y;   // 0..511
    const int a  = id & 7;
    const int r  = id >> 3;          // 0..63
    const int nb = r & 7;
    const int pr = a * 8 + (r >> 3); // 0..63
    const int mb = pr & 31;
    const int ks = pr >> 5;          // 0..1
    gemm_core<0>(As, Bs, A, W, bias, 1.0f, nullptr, ks ? out1 : out0,
                 mb * 128, nb * 128, ks * 512, 512);
}

// ---------------------------------------------------------------------------
// Flash attention, S^T form: S^T = MFMA(A=K, B=Q); q on lm, keys on quad/regs.
//  BQ=128, no split-K; 8 wq waves x 16 q-rows; 16 serial key tiles with the
//  2-phase pipeline (stage kt+1 early, one barrier/iter); LDS 32KB.
//  - P^T in registers via cvt_pk (pi-permuted V^T from gemm MODE 2).
//  - lsum via all-ones-A MFMA; ls[0] is directly the softmax denominator.
// ---------------------------------------------------------------------------
__global__ __launch_bounds__(512, 4) void flash_attn_mfma(
    const short* __restrict__ qf_, const short* __restrict__ kf_,
    const short* __restrict__ vf_, const short* __restrict__ mf_,
    short* __restrict__ out)
{
    __shared__ short KV[2][2][4096];  // 32KB: [parity][K,V][8KB tile]

    const int tid  = threadIdx.x;
    const int wave = tid >> 6;           // wq: q sub-tile (16 rows)
    const int lane = tid & 63;
    const int quad = lane >> 4;
    const int lm   = lane & 15;

    const int id  = blockIdx.x;          // 0..511
    const int xcd = id & 7;
    const int idx = id >> 3;             // 0..63
    const int bh_i = xcd * 8 + (idx >> 3);   // 0..63
    const int b  = bh_i >> 4, h = bh_i & 15;
    const int qb = idx & 7;              // q block (128 rows)
    const int q0 = qb * BQ;
    const size_t bh = (size_t)bh_i;

    // staging: waves 0-3 stage the K tile (2KB chunks), waves 4-7 the V tile.
    const short* sbase = ((wave < 4) ? kf_ : vf_) + bh * 65536
                         + (wave & 3) * 1024 + lane * 8;
    short* dstb = &KV[0][0][0] + (wave >> 2) * 4096 + (wave & 3) * 1024;

    // Q fragments (lane-ordered coalesced loads) — used as B operand
    const short* qb_ = qf_ + (bh * 64 + qb * 8 + wave) * 1024;
    const frag8 qfa = *(const frag8*)&qb_[(quad * 16 + lm) * 8];
    const frag8 qfb = *(const frag8*)&qb_[((quad + 4) * 16 + lm) * 8];

    // transposed mask tiles: [q%16][key%16]; this lane: q=lm, keys=quad*4..+3
    const short* mrow = mf_ + ((size_t)b * 64 + qb * 8 + wave) * (64 * 256)
                        + lm * 16 + quad * 4;

    // all-ones A fragment for the lsum MFMA
    union { int i[4]; frag8 f; } ones;
    ones.i[0] = ones.i[1] = ones.i[2] = ones.i[3] = 0x3F803F80;

    f32x4 of[4];
#pragma unroll
    for (int dc = 0; dc < 4; ++dc) of[dc] = (f32x4){0.f, 0.f, 0.f, 0.f};
    f32x4 ls = (f32x4){0.f, 0.f, 0.f, 0.f};

    // ---- prologue: stage kt=0 into parity 0; prefetch mask(kt=0) ----
    glds16(sbase,       dstb);
    glds16(sbase + 512, dstb + 512);
    short4v mb[4];
#pragma unroll
    for (int kc = 0; kc < 4; ++kc)
        mb[kc] = *(const short4v*)&mrow[kc * 256];
    __syncthreads();                     // drains prologue stage

    for (int kt = 0; kt < 16; ++kt) {
        const int cur = kt & 1;

        // issue next tile's stage EARLY — latency hides under compute below
        if (kt < 15) {
            short* nd = dstb + (cur ^ 1) * 8192;
            glds16(sbase + (kt + 1) * 4096,       nd);
            glds16(sbase + (kt + 1) * 4096 + 512, nd + 512);
        }
        // current mask to working regs; prefetch next tile's mask
        short4v mc[4];
#pragma unroll
        for (int kc = 0; kc < 4; ++kc) mc[kc] = mb[kc];
        if (kt < 15) {
#pragma unroll
            for (int kc = 0; kc < 4; ++kc)
                mb[kc] = *(const short4v*)&mrow[((kt + 1) * 4 + kc) * 256];
        }

        // S^T = K Q^T + maskbias (acc-init): rows=keys, cols=q
        f32x4 s[4];
#pragma unroll
        for (int kc = 0; kc < 4; ++kc) {
            const short* kb = &KV[cur][0][kc * 1024];
            const frag8 kfa = *(const frag8*)&kb[(quad * 16 + lm) * 8];
            const frag8 kfb = *(const frag8*)&kb[((quad + 4) * 16 + lm) * 8];
            f32x4 a = (f32x4){ bf2f((unsigned short)mc[kc][0]),
                               bf2f((unsigned short)mc[kc][1]),
                               bf2f((unsigned short)mc[kc][2]),
                               bf2f((unsigned short)mc[kc][3]) };
            a = __builtin_amdgcn_mfma_f32_16x16x32_bf16(kfa, qfa, a, 0, 0, 0);
            a = __builtin_amdgcn_mfma_f32_16x16x32_bf16(kfb, qfb, a, 0, 0, 0);
            s[kc] = a;
        }

        // fixed-max softmax in place: s = exp2(s^T)
#pragma unroll
        for (int kc = 0; kc < 4; ++kc) {
            s[kc][0] = exp2f(s[kc][0]); s[kc][1] = exp2f(s[kc][1]);
            s[kc][2] = exp2f(s[kc][2]); s[kc][3] = exp2f(s[kc][3]);
        }

        // in-register P^T fragments: lane (quad g) holds keys kc*16+4g..+3 —
        // exactly the pi slots (G=g) of the B operand.
        union { int i[4]; frag8 f; } ua, ub;
        ua.i[0] = cvt_pk_bf16(s[0][0], s[0][1]);
        ua.i[1] = cvt_pk_bf16(s[0][2], s[0][3]);
        ua.i[2] = cvt_pk_bf16(s[1][0], s[1][1]);
        ua.i[3] = cvt_pk_bf16(s[1][2], s[1][3]);
        ub.i[0] = cvt_pk_bf16(s[2][0], s[2][1]);
        ub.i[1] = cvt_pk_bf16(s[2][2], s[2][3]);
        ub.i[2] = cvt_pk_bf16(s[3][0], s[3][1]);
        ub.i[3] = cvt_pk_bf16(s[3][2], s[3][3]);

        __builtin_amdgcn_s_setprio(1);
#pragma unroll
        for (int dc = 0; dc < 4; ++dc) {
            const frag8 v0 = *(const frag8*)&KV[cur][1][(dc * 4 + quad) * 128 + lm * 8];
            const frag8 v1 = *(const frag8*)&KV[cur][1][((4 + dc) * 4 + quad) * 128 + lm * 8];
            of[dc] = __builtin_amdgcn_mfma_f32_16x16x32_bf16(v0, ua.f, of[dc], 0, 0, 0);
            of[dc] = __builtin_amdgcn_mfma_f32_16x16x32_bf16(v1, ub.f, of[dc], 0, 0, 0);
        }
        // lsum: D[r][q] = sum_k P[k][q] for every r (A = ones)
        ls = __builtin_amdgcn_mfma_f32_16x16x32_bf16(ones.f, ua.f, ls, 0, 0, 0);
        ls = __builtin_amdgcn_mfma_f32_16x16x32_bf16(ones.f, ub.f, ls, 0, 0, 0);
        __builtin_amdgcn_s_setprio(0);

        // single end-of-iter barrier: next stage drained (vmcnt0) AND all
        // waves done reading KV[cur] (overwritten at kt+2).
        __syncthreads();
    }

    // full denominator is lane-local (no key split)
    const float inv = 1.0f / ls[0];

    // O^T C-layout: row = d = dc*16 + quad*4 + rr, col = q = lm.
    short* ob = out + ((size_t)b * T_SEQ + q0 + wave * 16 + lm) * EMB + h * HD;
#pragma unroll
    for (int dc = 0; dc < 4; ++dc) {
        *(short4v*)&ob[dc * 16 + quad * 4] =
            pack4(of[dc][0] * inv, of[dc][1] * inv,
                  of[dc][2] * inv, of[dc][3] * inv);
    }
}

// ---------------------------------------------------------------------------
// LayerNorm over last dim (1024); sums the two split-K partials of the Wo
// projection (swapped MODE 0 layout: ((m>>4)*64+(n>>4))*256+(m&15)*16+(n&15)
// -> float4 reads), writes row-major.
// ---------------------------------------------------------------------------
__global__ __launch_bounds__(256) void layernorm_k(
    const float* __restrict__ x0, const float* __restrict__ x1,
    const float* __restrict__ gamma, const float* __restrict__ beta,
    float* __restrict__ out)
{
    __shared__ float ws1[4], ws2[4];
    const int tid = threadIdx.x;
    const int row = blockIdx.x;

    const size_t ix = ((size_t)(row >> 4) * 64 + (tid >> 2)) * 256 +
                      (row & 15) * 16 + (tid & 3) * 4;
    const float4 v1 = *(const float4*)&x0[ix];
    const float4 v2 = *(const float4*)&x1[ix];
    float4 v;
    v.x = v1.x + v2.x; v.y = v1.y + v2.y;
    v.z = v1.z + v2.z; v.w = v1.w + v2.w;

    float s  = v.x + v.y + v.z + v.w;
    float ss = v.x * v.x + v.y * v.y + v.z * v.z + v.w * v.w;
#pragma unroll
    for (int off = 32; off > 0; off >>= 1) {
        s  += __shfl_down(s, off);
        ss += __shfl_down(ss, off);
    }
    if ((tid & 63) == 0) { ws1[tid >> 6] = s; ws2[tid >> 6] = ss; }
    __syncthreads();
    if (tid == 0) {
        const float a = ws1[0] + ws1[1] + ws1[2] + ws1[3];
        const float bsum = ws2[0] + ws2[1] + ws2[2] + ws2[3];
        const float mu = a * (1.0f / EMB);
        const float var = bsum * (1.0f / EMB) - mu * mu;
        ws1[0] = mu;
        ws2[0] = rsqrtf(var + 1e-5f);
    }
    __syncthreads();
    const float mu = ws1[0], rstd = ws2[0];

    const float4 g = *(const float4*)&gamma[tid * 4];
    const float4 bt = *(const float4*)&beta[tid * 4];
    float4 r;
    r.x = (v.x - mu) * rstd * g.x + bt.x;
    r.y = (v.y - mu) * rstd * g.y + bt.y;
    r.z = (v.z - mu) * rstd * g.z + bt.z;
    r.w = (v.w - mu) * rstd * g.w + bt.w;
    *(float4*)&out[(size_t)row * EMB + tid * 4] = r;
}

// ---------------------------------------------------------------------------
extern "C" void kernel_launch(void* const* d_in, const int* in_sizes, int n_in,
                              void* d_out, int out_size, void* d_ws, size_t ws_size,
                              hipStream_t stream) {
    const float* query = (const float*)d_in[0];
    const float* key_i = (const float*)d_in[1];
    const float* value = (const float*)d_in[2];
    const int*   mask  = (const int*)d_in[3];
    const float* Wq = (const float*)d_in[4];
    const float* bq = (const float*)d_in[5];
    const float* Wk = (const float*)d_in[6];
    const float* bk = (const float*)d_in[7];
    const float* Wv = (const float*)d_in[8];
    const float* bv = (const float*)d_in[9];
    const float* Wo = (const float*)d_in[10];
    const float* bo = (const float*)d_in[11];
    const float* gamma = (const float*)d_in[12];
    const float* beta  = (const float*)d_in[13];

    const size_t SZ = (size_t)NB * T_SEQ * EMB;   // 4.19M elements
    const size_t WZ = (size_t)EMB * EMB;          // 1.05M elements
    short* sws = (short*)d_ws;
    short* q_bf  = sws;               // dead after gemm_qkv; attnb overlays
    short* k_bf  = sws + SZ;          // dead after gemm_qkv; projb overlays
    short* v_bf  = sws + 2 * SZ;
    short* w_bf  = sws + 3 * SZ;      // Wq,Wk,Wv,Wo bf16 (4*WZ == SZ)
    short* qh    = sws + 4 * SZ;      // Q A-frag layout; dead after flash
    short* kh    = sws + 5 * SZ;      // K A-frag layout; dead after flash
    short* vh    = sws + 6 * SZ;      // V^T frag layout (pi-permuted)
    short* maskb = sws + 7 * SZ;      // bf16 bias, transposed frag tiles
    short* attnb = q_bf;
    float* projb  = (float*)(sws + SZ);      // k_bf/v_bf region (dead)
    float* projb2 = (float*)(sws + 4 * SZ);  // qh/kh region (dead after flash)

    // 1. fused preprocessing (inputs + weights + mask), one launch
    ConvArgs ca;
    ca.src[0] = query; ca.dst[0] = q_bf;
    ca.src[1] = key_i; ca.dst[1] = k_bf;
    ca.src[2] = value; ca.dst[2] = v_bf;
    ca.src[3] = Wq;    ca.dst[3] = w_bf;
    ca.src[4] = Wk;    ca.dst[4] = w_bf + WZ;
    ca.src[5] = Wv;    ca.dst[5] = w_bf + 2 * WZ;
    ca.src[6] = Wo;    ca.dst[6] = w_bf + 3 * WZ;
    ca.mask = mask; ca.maskb = maskb;
    convert_all<<<dim3(12288), 256, 0, stream>>>(ca);

    // 2. QKV projections; Q pre-scaled by 0.125*log2e; frag-layout outputs
    QkvArgs qa;
    qa.g[0] = { q_bf, w_bf,          bq, qh, QSCALE };
    qa.g[1] = { k_bf, w_bf + WZ,     bk, kh, 1.0f };
    qa.g[2] = { v_bf, w_bf + 2 * WZ, bv, vh, 1.0f };
    gemm_qkv<<<dim3(EMB / 128, NB * T_SEQ / 128, 3), 512, 0, stream>>>(qa);

    // 3. flash attention (BQ=128, 2-phase pipeline, XCD grid)
    flash_attn_mfma<<<dim3(T_SEQ / BQ * NH * NB), 512, 0, stream>>>(qh, kh, vh, maskb, attnb);

    // 4. output projection, split-K x2 (fp32 swapped C-order partials)
    gemm_wo<<<dim3(8, 64), 512, 0, stream>>>(attnb, w_bf + 3 * WZ, bo, projb, projb2);

    // 5. layernorm (sums partials, writes row-major)
    layernorm_k<<<dim3(NB * T_SEQ), 256, 0, stream>>>(projb, projb2, gamma, beta, (float*)d_out);
}